// Round 1
// baseline (108.147 us; speedup 1.0000x reference)
//
#include <hip/hip_runtime.h>
#include <math.h>

#define NS 512
#define DE 512
#define NCL 5

// ---------------------------------------------------------------------------
// K1: row-normalize prediction -> xn ; block 0 zeroes accumulators
// ---------------------------------------------------------------------------
__global__ __launch_bounds__(256) void k_normalize(const float* __restrict__ pred,
                                                   float* __restrict__ xn,
                                                   float* __restrict__ gsum,
                                                   unsigned int* __restrict__ gnz) {
    const int i = blockIdx.x;
    const int tid = threadIdx.x;
    if (i == 0 && tid == 0) { gsum[0] = 0.0f; gnz[0] = 0u; }

    float a0 = pred[i * DE + tid];
    float a1 = pred[i * DE + tid + 256];

    __shared__ float red[256];
    red[tid] = a0 * a0 + a1 * a1;
    __syncthreads();
    for (int s = 128; s > 0; s >>= 1) {
        if (tid < s) red[tid] += red[tid + s];
        __syncthreads();
    }
    float inv = 1.0f / fmaxf(sqrtf(red[0]), 1e-8f);
    xn[i * DE + tid]       = a0 * inv;
    xn[i * DE + tid + 256] = a1 * inv;
}

// ---------------------------------------------------------------------------
// K2: cos = xn * xn^T  (fp32, 64x64 tile, BK=16, 4x4 per thread)
// LDS stored transposed [kk][row] so fragments are ds_read_b128.
// ---------------------------------------------------------------------------
__global__ __launch_bounds__(256) void k_gemm(const float* __restrict__ xn,
                                              float* __restrict__ cosm) {
    __shared__ float As[16][68];   // [kk][row], pad to 68 (keeps 16B align, breaks conflicts)
    __shared__ float Bs[16][68];

    const int tid = threadIdx.x;
    const int tx = tid & 15, ty = tid >> 4;
    const int row0 = blockIdx.y * 64, col0 = blockIdx.x * 64;
    const int lr = tid >> 2;          // 0..63: row within tile for loading
    const int lc = (tid & 3) * 4;     // 0,4,8,12: k-offset for loading

    float c[4][4] = {};

    for (int kb = 0; kb < DE; kb += 16) {
        float4 av = *(const float4*)&xn[(row0 + lr) * DE + kb + lc];
        float4 bv = *(const float4*)&xn[(col0 + lr) * DE + kb + lc];
        __syncthreads();
        As[lc + 0][lr] = av.x; As[lc + 1][lr] = av.y;
        As[lc + 2][lr] = av.z; As[lc + 3][lr] = av.w;
        Bs[lc + 0][lr] = bv.x; Bs[lc + 1][lr] = bv.y;
        Bs[lc + 2][lr] = bv.z; Bs[lc + 3][lr] = bv.w;
        __syncthreads();
#pragma unroll
        for (int kk = 0; kk < 16; kk++) {
            float4 a = *(const float4*)&As[kk][ty * 4];
            float4 b = *(const float4*)&Bs[kk][tx * 4];
            c[0][0] = fmaf(a.x, b.x, c[0][0]); c[0][1] = fmaf(a.x, b.y, c[0][1]);
            c[0][2] = fmaf(a.x, b.z, c[0][2]); c[0][3] = fmaf(a.x, b.w, c[0][3]);
            c[1][0] = fmaf(a.y, b.x, c[1][0]); c[1][1] = fmaf(a.y, b.y, c[1][1]);
            c[1][2] = fmaf(a.y, b.z, c[1][2]); c[1][3] = fmaf(a.y, b.w, c[1][3]);
            c[2][0] = fmaf(a.z, b.x, c[2][0]); c[2][1] = fmaf(a.z, b.y, c[2][1]);
            c[2][2] = fmaf(a.z, b.z, c[2][2]); c[2][3] = fmaf(a.z, b.w, c[2][3]);
            c[3][0] = fmaf(a.w, b.x, c[3][0]); c[3][1] = fmaf(a.w, b.y, c[3][1]);
            c[3][2] = fmaf(a.w, b.z, c[3][2]); c[3][3] = fmaf(a.w, b.w, c[3][3]);
        }
    }
#pragma unroll
    for (int m = 0; m < 4; m++) {
        float4 o = make_float4(c[m][0], c[m][1], c[m][2], c[m][3]);
        *(float4*)&cosm[(row0 + ty * 4 + m) * NS + col0 + tx * 4] = o;
    }
}

// ---------------------------------------------------------------------------
// K3: per-anchor loss. Block i handles anchor i.
//   v[j] = cos[i,j] + |cp_i - cp_j|  for negatives, -1e30 otherwise
//   s[k] = sum_j relu(v[j] - cos[i,k]) for compacted positive k's
//   atomicAdd(gsum, sum_k s[k]/max(negcount,1)); atomicAdd(gnz, #{s[k]!=0})
// ---------------------------------------------------------------------------
__global__ __launch_bounds__(256) void k_loss(const float* __restrict__ cosm,
                                              const int* __restrict__ target,
                                              const float* __restrict__ draw,
                                              float* __restrict__ gsum,
                                              unsigned int* __restrict__ gnz) {
    const int i = blockIdx.x;
    const int tid = threadIdx.x;

    __shared__ float v[NS];
    __shared__ float ck[NS];
    __shared__ int   pk[NS];
    __shared__ float redf[256];
    __shared__ int   redi[256];
    __shared__ unsigned int pcount;

    // class positions from softplus-parameterized gaps (redundant per thread, cheap)
    float cp[NCL];
    cp[0] = 0.0f;
#pragma unroll
    for (int c = 0; c < NCL - 1; c++) cp[c + 1] = cp[c] + log1pf(expf(draw[c]));

    const int ti = target[i];
    const float cpi = cp[ti];

    if (tid == 0) pcount = 0u;
    __syncthreads();

    int ncnt = 0;
#pragma unroll
    for (int jj = 0; jj < 2; jj++) {
        int j = tid + jj * 256;
        int tj = target[j];
        float c = cosm[i * NS + j];
        ck[j] = c;
        bool neg = (tj != ti);
        v[j] = neg ? (c + fabsf(cpi - cp[tj])) : -1e30f;
        ncnt += neg ? 1 : 0;
        if (!neg && j != i) {                  // positive: same label, not self
            unsigned int idx = atomicAdd(&pcount, 1u);
            pk[idx] = j;
        }
    }
    redi[tid] = ncnt;
    __syncthreads();
    for (int s = 128; s > 0; s >>= 1) {
        if (tid < s) redi[tid] += redi[tid + s];
        __syncthreads();
    }
    const int negcount = redi[0];
    const unsigned int npos = pcount;
    __syncthreads();   // protect redi reuse below

    float ssum = 0.0f;
    int nzc = 0;
    for (unsigned int p = tid; p < npos; p += 256) {
        const float c_k = ck[pk[p]];
        float s = 0.0f;
#pragma unroll 8
        for (int j = 0; j < NS; j++) s += fmaxf(v[j] - c_k, 0.0f);
        ssum += s;
        if (s != 0.0f) nzc++;
    }

    redf[tid] = ssum;
    redi[tid] = nzc;
    __syncthreads();
    for (int s = 128; s > 0; s >>= 1) {
        if (tid < s) { redf[tid] += redf[tid + s]; redi[tid] += redi[tid + s]; }
        __syncthreads();
    }
    if (tid == 0) {
        int denom = negcount > 1 ? negcount : 1;
        if (redf[0] != 0.0f || redi[0] != 0) {
            atomicAdd(gsum, redf[0] / (float)denom);
            atomicAdd(gnz, (unsigned int)redi[0]);
        }
    }
}

// ---------------------------------------------------------------------------
// K4: finalize  out = gsum / max(gnz, 1)
// ---------------------------------------------------------------------------
__global__ __launch_bounds__(64) void k_final(const float* __restrict__ gsum,
                                              const unsigned int* __restrict__ gnz,
                                              float* __restrict__ out) {
    if (threadIdx.x == 0) {
        unsigned int n = gnz[0];
        out[0] = gsum[0] / (float)(n > 1u ? n : 1u);
    }
}

extern "C" void kernel_launch(void* const* d_in, const int* in_sizes, int n_in,
                              void* d_out, int out_size, void* d_ws, size_t ws_size,
                              hipStream_t stream) {
    const float* pred   = (const float*)d_in[0];
    const float* draw   = (const float*)d_in[1];
    const int*   target = (const int*)d_in[2];
    float* out = (float*)d_out;

    float* ws   = (float*)d_ws;
    float* xn   = ws;                       // 512*512 floats
    float* cosm = ws + NS * DE;             // 512*512 floats
    float* gsum = ws + 2 * NS * DE;         // 1 float
    unsigned int* gnz = (unsigned int*)(ws + 2 * NS * DE + 1);

    hipLaunchKernelGGL(k_normalize, dim3(NS), dim3(256), 0, stream, pred, xn, gsum, gnz);
    hipLaunchKernelGGL(k_gemm, dim3(8, 8), dim3(256), 0, stream, xn, cosm);
    hipLaunchKernelGGL(k_loss, dim3(NS), dim3(256), 0, stream, cosm, target, draw, gsum, gnz);
    hipLaunchKernelGGL(k_final, dim3(1), dim3(64), 0, stream, gsum, gnz, out);
}

// Round 2
// 94.241 us; speedup vs baseline: 1.1476x; 1.1476x over previous
//
#include <hip/hip_runtime.h>
#include <math.h>

#define NS 512
#define DE 512
#define NCL 5
#define KSPLIT 4

// ---------------------------------------------------------------------------
// K1: split-K partial Gram matrix  part[z] = pred[:, z-range] * pred[:, z-range]^T
//     (raw pred, NOT normalized — norms recovered from diag in K2)
//     Block (0,0,0) zeroes the global accumulators + ticket.
//     64x64 tile, BK=16, 4x4 per thread, grid (8,8,KSPLIT).
// ---------------------------------------------------------------------------
__global__ __launch_bounds__(256) void k_gemm(const float* __restrict__ pred,
                                              float* __restrict__ part,
                                              float* __restrict__ gsum,
                                              unsigned int* __restrict__ gnz,
                                              unsigned int* __restrict__ ticket) {
    const int tid = threadIdx.x;
    if (blockIdx.x == 0 && blockIdx.y == 0 && blockIdx.z == 0 && tid == 0) {
        *gsum = 0.0f; *gnz = 0u; *ticket = 0u;
    }

    __shared__ float As[16][68];   // [kk][row], padded
    __shared__ float Bs[16][68];

    const int tx = tid & 15, ty = tid >> 4;
    const int row0 = blockIdx.y * 64, col0 = blockIdx.x * 64;
    const int kz0 = blockIdx.z * (DE / KSPLIT);
    const int lr = tid >> 2;          // 0..63: row within tile
    const int lc = (tid & 3) * 4;     // 0,4,8,12: k-offset

    float c[4][4] = {};

    for (int kb = 0; kb < DE / KSPLIT; kb += 16) {
        float4 av = *(const float4*)&pred[(row0 + lr) * DE + kz0 + kb + lc];
        float4 bv = *(const float4*)&pred[(col0 + lr) * DE + kz0 + kb + lc];
        __syncthreads();
        As[lc + 0][lr] = av.x; As[lc + 1][lr] = av.y;
        As[lc + 2][lr] = av.z; As[lc + 3][lr] = av.w;
        Bs[lc + 0][lr] = bv.x; Bs[lc + 1][lr] = bv.y;
        Bs[lc + 2][lr] = bv.z; Bs[lc + 3][lr] = bv.w;
        __syncthreads();
#pragma unroll
        for (int kk = 0; kk < 16; kk++) {
            float4 a = *(const float4*)&As[kk][ty * 4];
            float4 b = *(const float4*)&Bs[kk][tx * 4];
            c[0][0] = fmaf(a.x, b.x, c[0][0]); c[0][1] = fmaf(a.x, b.y, c[0][1]);
            c[0][2] = fmaf(a.x, b.z, c[0][2]); c[0][3] = fmaf(a.x, b.w, c[0][3]);
            c[1][0] = fmaf(a.y, b.x, c[1][0]); c[1][1] = fmaf(a.y, b.y, c[1][1]);
            c[1][2] = fmaf(a.y, b.z, c[1][2]); c[1][3] = fmaf(a.y, b.w, c[1][3]);
            c[2][0] = fmaf(a.z, b.x, c[2][0]); c[2][1] = fmaf(a.z, b.y, c[2][1]);
            c[2][2] = fmaf(a.z, b.z, c[2][2]); c[2][3] = fmaf(a.z, b.w, c[2][3]);
            c[3][0] = fmaf(a.w, b.x, c[3][0]); c[3][1] = fmaf(a.w, b.y, c[3][1]);
            c[3][2] = fmaf(a.w, b.z, c[3][2]); c[3][3] = fmaf(a.w, b.w, c[3][3]);
        }
    }

    float* outp = part + (size_t)blockIdx.z * NS * NS;
#pragma unroll
    for (int m = 0; m < 4; m++) {
        float4 o = make_float4(c[m][0], c[m][1], c[m][2], c[m][3]);
        *(float4*)&outp[(row0 + ty * 4 + m) * NS + col0 + tx * 4] = o;
    }
}

// ---------------------------------------------------------------------------
// K2: per-anchor loss + ticket-based finalize. Block i handles anchor i.
//   rn[j]   = 1/max(sqrt(sum_z part_z[j,j]), 1e-8)
//   cos_ij  = (sum_z part_z[i,j]) * rn[i] * rn[j]
//   v[j]    = cos_ij + |cp_i - cp_j|  for negatives, -1e30 otherwise
//   s[k]    = sum_j relu(v[j] - cos_ik) over compacted positive k's
//   gsum   += sum_k s[k]/max(negcount,1); gnz += #{s[k]!=0}
//   last block: out = gsum / max(gnz, 1)
// ---------------------------------------------------------------------------
__global__ __launch_bounds__(256) void k_loss(const float* __restrict__ part,
                                              const int* __restrict__ target,
                                              const float* __restrict__ draw,
                                              float* __restrict__ gsum,
                                              unsigned int* __restrict__ gnz,
                                              unsigned int* __restrict__ ticket,
                                              float* __restrict__ out) {
    const int i = blockIdx.x;
    const int tid = threadIdx.x;

    __shared__ float rn[NS];
    __shared__ float v[NS];
    __shared__ float ck[NS];
    __shared__ int   pk[NS];
    __shared__ float redf[256];
    __shared__ int   redi[256];
    __shared__ unsigned int pcount;

    const float* p0 = part;
    const float* p1 = part + NS * NS;
    const float* p2 = part + 2 * NS * NS;
    const float* p3 = part + 3 * NS * NS;

    // row inverse-norms from the Gram diagonal
#pragma unroll
    for (int jj = 0; jj < 2; jj++) {
        int j = tid + jj * 256;
        float nsq = p0[j * NS + j] + p1[j * NS + j] + p2[j * NS + j] + p3[j * NS + j];
        rn[j] = 1.0f / fmaxf(sqrtf(nsq), 1e-8f);
    }
    if (tid == 0) pcount = 0u;

    // ordinal class positions (softplus gaps), redundant per thread
    float cp[NCL];
    cp[0] = 0.0f;
#pragma unroll
    for (int c = 0; c < NCL - 1; c++) cp[c + 1] = cp[c] + log1pf(expf(draw[c]));
    const int ti = target[i];
    const float cpi = cp[ti];
    __syncthreads();

    const float rni = rn[i];
    int ncnt = 0;
#pragma unroll
    for (int jj = 0; jj < 2; jj++) {
        int j = tid + jj * 256;
        int tj = target[j];
        float g = p0[i * NS + j] + p1[i * NS + j] + p2[i * NS + j] + p3[i * NS + j];
        float c = g * rni * rn[j];
        ck[j] = c;
        bool neg = (tj != ti);
        v[j] = neg ? (c + fabsf(cpi - cp[tj])) : -1e30f;
        ncnt += neg ? 1 : 0;
        if (!neg && j != i) {                       // positive: same label, not self
            pk[atomicAdd(&pcount, 1u)] = j;
        }
    }
    redi[tid] = ncnt;
    __syncthreads();
    for (int s = 128; s > 0; s >>= 1) {
        if (tid < s) redi[tid] += redi[tid + s];
        __syncthreads();
    }
    const int negcount = redi[0];
    const unsigned int npos = pcount;
    __syncthreads();   // protect redi reuse

    float ssum = 0.0f;
    int nzc = 0;
    const float4* v4 = (const float4*)v;
    for (unsigned int p = tid; p < npos; p += 256) {
        const float c_k = ck[pk[p]];
        float s0 = 0.0f, s1 = 0.0f;
#pragma unroll 4
        for (int jq = 0; jq < NS / 4; jq++) {
            float4 w = v4[jq];
            s0 += fmaxf(w.x - c_k, 0.0f) + fmaxf(w.y - c_k, 0.0f);
            s1 += fmaxf(w.z - c_k, 0.0f) + fmaxf(w.w - c_k, 0.0f);
        }
        float s = s0 + s1;
        ssum += s;
        if (s != 0.0f) nzc++;
    }

    redf[tid] = ssum;
    redi[tid] = nzc;
    __syncthreads();
    for (int s = 128; s > 0; s >>= 1) {
        if (tid < s) { redf[tid] += redf[tid + s]; redi[tid] += redi[tid + s]; }
        __syncthreads();
    }
    if (tid == 0) {
        int denom = negcount > 1 ? negcount : 1;
        if (redf[0] != 0.0f || redi[0] != 0) {
            atomicAdd(gsum, redf[0] / (float)denom);
            atomicAdd(gnz, (unsigned int)redi[0]);
        }
        __threadfence();
        unsigned int t = atomicAdd(ticket, 1u);
        if (t == (unsigned int)(gridDim.x - 1)) {
            // all other blocks' accumulations are visible (release via threadfence
            // before their ticket add). Read via atomic to bypass stale L1.
            float s = atomicAdd(gsum, 0.0f);
            unsigned int n = atomicAdd(gnz, 0u);
            out[0] = s / (float)(n > 1u ? n : 1u);
        }
    }
}

extern "C" void kernel_launch(void* const* d_in, const int* in_sizes, int n_in,
                              void* d_out, int out_size, void* d_ws, size_t ws_size,
                              hipStream_t stream) {
    const float* pred   = (const float*)d_in[0];
    const float* draw   = (const float*)d_in[1];
    const int*   target = (const int*)d_in[2];
    float* out = (float*)d_out;

    float* ws   = (float*)d_ws;
    float* part = ws;                                   // KSPLIT * 512*512 floats
    float* gsum = ws + KSPLIT * NS * NS;                // 1 float
    unsigned int* gnz    = (unsigned int*)(gsum + 1);
    unsigned int* ticket = (unsigned int*)(gsum + 2);

    hipLaunchKernelGGL(k_gemm, dim3(8, 8, KSPLIT), dim3(256), 0, stream,
                       pred, part, gsum, gnz, ticket);
    hipLaunchKernelGGL(k_loss, dim3(NS), dim3(256), 0, stream,
                       part, target, draw, gsum, gnz, ticket, out);
}